// Round 10
// baseline (85.590 us; speedup 1.0000x reference)
//
#include <hip/hip_runtime.h>
#include <hip/hip_bf16.h>

#define VOCAB 100000
#define HALF  256      // HIDDEN/2
#define NC    256      // NUM_CLUSTERS
#define NTOK  16384    // B*S
#define SEGSZ 3200     // ids per segment
#define NSEG  32
#define NHB   16       // histogram/scatter blocks

using frag  = __attribute__((ext_vector_type(8))) short;   // 8 bf16 (A/B operand)
using f32x4 = __attribute__((ext_vector_type(4))) float;   // C/D

static __device__ inline unsigned bfpk(float lo, float hi) {
    union { __hip_bfloat162 h2; unsigned u; } cv;
    cv.h2.x = __float2bfloat16(lo);
    cv.h2.y = __float2bfloat16(hi);
    return cv.u;
}

// ---------------- prep1: 32-seg histograms + coarse transpose ----------------
__global__ __launch_bounds__(1024)
void prep1(const int* __restrict__ ids, const float* __restrict__ coarse_w,
           int* __restrict__ partial, ushort* __restrict__ cT)
{
    __shared__ float tile[64][65];
    __shared__ int lh[NSEG];
    const int tid = threadIdx.x;
    const int b   = blockIdx.x;

    if (b < NHB) {
        if (tid < NSEG) lh[tid] = 0;
        __syncthreads();
        atomicAdd(&lh[ids[b * 1024 + tid] / SEGSZ], 1);
        __syncthreads();
        if (tid < NSEG) partial[b * NSEG + tid] = lh[tid];
    } else {
        const int bt = b - NHB;
        const int ci = (bt >> 2) * 64, hi = (bt & 3) * 64;
#pragma unroll
        for (int p = 0; p < 4; ++p) {
            const int idx = tid + p * 1024;
            const int cl = idx >> 6, hl = idx & 63;
            tile[cl][hl] = coarse_w[(size_t)(ci + cl) * HALF + hi + hl];
        }
        __syncthreads();
#pragma unroll
        for (int p = 0; p < 4; ++p) {
            const int idx = tid + p * 1024;
            const int hl = idx >> 6, cl = idx & 63;
            __hip_bfloat16 v = __float2bfloat16(tile[cl][hl]);
            cT[(size_t)(hi + hl) * NC + ci + cl] = *reinterpret_cast<ushort*>(&v);
        }
    }
}

// ---------------- prep2: 32-wide offsets + rank scatter ----------------
__global__ __launch_bounds__(1024)
void prep2(const int* __restrict__ ids, const int* __restrict__ partial,
           int* __restrict__ seg_off, int* __restrict__ stok, int* __restrict__ sidv)
{
    __shared__ int part_l[NHB][NSEG];
    __shared__ int segoff[NSEG + 1];
    __shared__ int basebs[NSEG];
    __shared__ int cnt[NSEG];
    const int tid = threadIdx.x;
    const int b   = blockIdx.x;

    if (tid < NHB * NSEG) part_l[tid >> 5][tid & 31] = partial[tid];
    __syncthreads();

    if (tid < NSEG) {
        int tot_before = 0, tot_s = 0, base = 0;
        for (int bb = 0; bb < NHB; ++bb) {
            const int v = part_l[bb][tid];
            tot_s += v;
            if (bb < b) base += v;
        }
        for (int s = 0; s < NSEG; ++s)
            if (s < tid)
                for (int bb = 0; bb < NHB; ++bb) tot_before += part_l[bb][s];
        segoff[tid] = tot_before;
        basebs[tid] = base;
        cnt[tid]    = 0;
        if (tid == NSEG - 1) segoff[NSEG] = tot_before + tot_s;
    }
    __syncthreads();

    const int t  = b * 1024 + tid;
    const int id = ids[t];
    const int sg = id / SEGSZ;
    const int r  = atomicAdd(&cnt[sg], 1);
    const int pos = segoff[sg] + basebs[sg] + r;
    stok[pos] = t;
    sidv[pos] = id;

    if (b == 0 && tid <= NSEG) seg_off[tid] = segoff[tid];
}

// ---------------- Kernel A v2: long-stream gather with register dbuf ----------------
// block = (row r, eighth e): streams segments e*4..e*4+3 (51.2 KB sequential).
// Prefetch seg k+1 into regs while looking up seg k -> loads always in flight.
__global__ __launch_bounds__(256)
void gather_rows(const float* __restrict__ cluster_w,
                 const float* __restrict__ cluster_b,
                 const int*   __restrict__ sidv,
                 const int*   __restrict__ seg_off,
                 __hip_bfloat16* __restrict__ logT)      // [NC][NTOK]
{
    __shared__ float seg[SEGSZ];
    const int tid = threadIdx.x;
    const int r   = blockIdx.x >> 3;
    const int e   = blockIdx.x & 7;
    const float bias = cluster_b[r];
    const float* rowp = cluster_w + (size_t)r * VOCAB;

    int s     = e * 4;
    int sbase = s * SEGSZ;
    int nf4   = min(SEGSZ, VOCAB - sbase) >> 2;

    float4 pf[4];
#pragma unroll
    for (int p = 0; p < 4; ++p) {
        const int i = tid + p * 256;
        if (i < nf4) pf[p] = *reinterpret_cast<const float4*>(rowp + sbase + 4 * i);
    }

    for (int k = 0; k < 4; ++k, ++s) {
        // commit current prefetch to LDS
#pragma unroll
        for (int p = 0; p < 4; ++p) {
            const int i = tid + p * 256;
            if (i < nf4) *reinterpret_cast<float4*>(&seg[4 * i]) = pf[p];
        }
        const int sb_cur = sbase;
        const int lo = seg_off[s];
        const int hi = seg_off[s + 1];

        // issue next segment's loads (in flight across the barrier + lookup)
        if (k < 3) {
            sbase += SEGSZ;
            nf4 = min(SEGSZ, VOCAB - sbase) >> 2;
#pragma unroll
            for (int p = 0; p < 4; ++p) {
                const int i = tid + p * 256;
                if (i < nf4) pf[p] = *reinterpret_cast<const float4*>(rowp + sbase + 4 * i);
            }
        }
        __syncthreads();   // LDS writes visible

        for (int i = lo + tid; i < hi; i += 256)
            logT[(size_t)r * NTOK + i] = __float2bfloat16(seg[sidv[i] - sb_cur] + bias);
        __syncthreads();   // LDS consumed before next commit
    }
}

// ---------------- Kernel B: softmax + fine + MFMA mixture (unchanged) ----------------
__global__ __launch_bounds__(512)
void mix_mfma(const ushort* __restrict__ logT,     // [NC][NTOK] bf16 bits
              const float*  __restrict__ fine_w,
              const ushort* __restrict__ cT,       // [HALF][NC] bf16 bits, L2-hot
              const int*    __restrict__ stok,
              const int*    __restrict__ sidv,
              float*        __restrict__ out)
{
    __shared__ uint4 ldsA[32][33];
    __shared__ float redu[32][17];
    __shared__ int stok_l[32], sid_l[32];

    const int tid  = threadIdx.x;
    const int base = blockIdx.x * 32;

    if (tid < 32) { stok_l[tid] = stok[base + tid]; sid_l[tid] = sidv[base + tid]; }

    const int s = tid & 31;
    const int g = tid >> 5;
    float v[16];
#pragma unroll
    for (int i = 0; i < 16; ++i) {
        const unsigned u = logT[(size_t)(g * 16 + i) * NTOK + base + s];
        v[i] = __uint_as_float(u << 16);
    }
    float m = v[0];
#pragma unroll
    for (int i = 1; i < 16; ++i) m = fmaxf(m, v[i]);
    redu[s][g] = m;
    __syncthreads();
    float M = redu[s][0];
#pragma unroll
    for (int i = 1; i < 16; ++i) M = fmaxf(M, redu[s][i]);
    __syncthreads();
    float sum = 0.f;
#pragma unroll
    for (int i = 0; i < 16; ++i) { v[i] = __expf(v[i] - M); sum += v[i]; }
    redu[s][g] = sum;
    __syncthreads();
    float tot = 0.f;
#pragma unroll
    for (int i = 0; i < 16; ++i) tot += redu[s][i];
    const float inv = 1.f / tot;

    {
        uint4 u0, u1;
        u0.x = bfpk(v[0] * inv,  v[1] * inv);
        u0.y = bfpk(v[2] * inv,  v[3] * inv);
        u0.z = bfpk(v[4] * inv,  v[5] * inv);
        u0.w = bfpk(v[6] * inv,  v[7] * inv);
        u1.x = bfpk(v[8] * inv,  v[9] * inv);
        u1.y = bfpk(v[10] * inv, v[11] * inv);
        u1.z = bfpk(v[12] * inv, v[13] * inv);
        u1.w = bfpk(v[14] * inv, v[15] * inv);
        ldsA[s][2 * g]     = u0;
        ldsA[s][2 * g + 1] = u1;
    }

    {
        const int sl = tid >> 4, l16 = tid & 15;
        const float4* fs = reinterpret_cast<const float4*>(fine_w + (size_t)sid_l[sl] * HALF);
        float4* fd = reinterpret_cast<float4*>(out + (size_t)stok_l[sl] * 512);
#pragma unroll
        for (int p = 0; p < 4; ++p) fd[l16 + 16 * p] = fs[l16 + 16 * p];
    }
    __syncthreads();

    const int w    = tid >> 6;
    const int lane = tid & 63;
    const int arow = (w & 1) * 16 + (lane & 15);
    const int ngrp = (w >> 1) * 4;
    f32x4 acc[4];
#pragma unroll
    for (int q = 0; q < 4; ++q) acc[q] = (f32x4){0.f, 0.f, 0.f, 0.f};

    for (int ch = 0; ch < 8; ++ch) {
        const frag a = *reinterpret_cast<const frag*>(&ldsA[arow][ch * 4 + (lane >> 4)]);
#pragma unroll
        for (int q = 0; q < 4; ++q) {
            const int n = (ngrp + q) * 16 + (lane & 15);
            const frag b = *reinterpret_cast<const frag*>(
                cT + (size_t)n * NC + ch * 32 + (lane >> 4) * 8);
            acc[q] = __builtin_amdgcn_mfma_f32_16x16x32_bf16(a, b, acc[q], 0, 0, 0);
        }
    }

#pragma unroll
    for (int q = 0; q < 4; ++q) {
        const int col = (ngrp + q) * 16 + (lane & 15);
#pragma unroll
        for (int r = 0; r < 4; ++r) {
            const int srow = (w & 1) * 16 + (lane >> 4) * 4 + r;
            out[(size_t)stok_l[srow] * 512 + 256 + col] = acc[q][r];
        }
    }
}

extern "C" void kernel_launch(void* const* d_in, const int* in_sizes, int n_in,
                              void* d_out, int out_size, void* d_ws, size_t ws_size,
                              hipStream_t stream) {
    const int*   ids       = (const int*)  d_in[0];
    const float* fine_w    = (const float*)d_in[1];
    const float* coarse_w  = (const float*)d_in[2];
    const float* cluster_w = (const float*)d_in[3];
    const float* cluster_b = (const float*)d_in[4];
    float*       out       = (float*)d_out;

    int* partial = (int*)d_ws;                    // [NHB*NSEG]
    int* seg_off = partial + NHB * NSEG;          // [NSEG+1] (pad 64)
    int* stok    = seg_off + 64;                  // [NTOK]
    int* sidv    = stok + NTOK;                   // [NTOK]
    __hip_bfloat16* logT = (__hip_bfloat16*)(sidv + NTOK);   // [NC*NTOK]
    ushort* cT = (ushort*)(logT + (size_t)NC * NTOK);        // [HALF*NC]

    const size_t need = (size_t)(NHB * NSEG + 64 + 2 * NTOK) * sizeof(int)
                      + (size_t)NC * NTOK * 2 + (size_t)HALF * NC * 2;
    if (ws_size < need) return;   // not expected

    hipLaunchKernelGGL(prep1, dim3(2 * NHB), dim3(1024), 0, stream,
                       ids, coarse_w, partial, cT);
    hipLaunchKernelGGL(prep2, dim3(NHB), dim3(1024), 0, stream,
                       ids, partial, seg_off, stok, sidv);
    hipLaunchKernelGGL(gather_rows, dim3(NC * 8), dim3(256), 0, stream,
                       cluster_w, cluster_b, sidv, seg_off, logT);
    hipLaunchKernelGGL(mix_mfma, dim3(NTOK / 32), dim3(512), 0, stream,
                       (const ushort*)logT, fine_w, cT, stok, sidv, out);
}

// Round 11
// 57.217 us; speedup vs baseline: 1.4959x; 1.4959x over previous
//
#include <hip/hip_runtime.h>
#include <hip/hip_bf16.h>

#define VOCAB 100000
#define HALF  256      // HIDDEN/2
#define NC    256      // NUM_CLUSTERS
#define NTOK  16384    // B*S
#define SEGSZ 3200     // ids per segment
#define NSEG  32
#define NHB   16       // histogram/scatter blocks

using frag  = __attribute__((ext_vector_type(8))) short;   // 8 bf16 (A/B operand)
using f32x4 = __attribute__((ext_vector_type(4))) float;   // C/D

static __device__ inline unsigned bfpk(float lo, float hi) {
    union { __hip_bfloat162 h2; unsigned u; } cv;
    cv.h2.x = __float2bfloat16(lo);
    cv.h2.y = __float2bfloat16(hi);
    return cv.u;
}

// async global->LDS, 16B/lane, no VGPR round-trip (size must be literal)
static __device__ inline void gload_lds16(const float* g, float* l) {
    __builtin_amdgcn_global_load_lds(
        (const __attribute__((address_space(1))) void*)g,
        (__attribute__((address_space(3))) void*)l, 16, 0, 0);
}

// ---------------- prep1: 32-seg histograms + coarse transpose ----------------
__global__ __launch_bounds__(1024)
void prep1(const int* __restrict__ ids, const float* __restrict__ coarse_w,
           int* __restrict__ partial, ushort* __restrict__ cT)
{
    __shared__ float tile[64][65];
    __shared__ int lh[NSEG];
    const int tid = threadIdx.x;
    const int b   = blockIdx.x;

    if (b < NHB) {
        if (tid < NSEG) lh[tid] = 0;
        __syncthreads();
        atomicAdd(&lh[ids[b * 1024 + tid] / SEGSZ], 1);
        __syncthreads();
        if (tid < NSEG) partial[b * NSEG + tid] = lh[tid];
    } else {
        const int bt = b - NHB;
        const int ci = (bt >> 2) * 64, hi = (bt & 3) * 64;
#pragma unroll
        for (int p = 0; p < 4; ++p) {
            const int idx = tid + p * 1024;
            const int cl = idx >> 6, hl = idx & 63;
            tile[cl][hl] = coarse_w[(size_t)(ci + cl) * HALF + hi + hl];
        }
        __syncthreads();
#pragma unroll
        for (int p = 0; p < 4; ++p) {
            const int idx = tid + p * 1024;
            const int hl = idx >> 6, cl = idx & 63;
            __hip_bfloat16 v = __float2bfloat16(tile[cl][hl]);
            cT[(size_t)(hi + hl) * NC + ci + cl] = *reinterpret_cast<ushort*>(&v);
        }
    }
}

// ---------------- prep2: 32-wide offsets + rank scatter ----------------
__global__ __launch_bounds__(1024)
void prep2(const int* __restrict__ ids, const int* __restrict__ partial,
           int* __restrict__ seg_off, int* __restrict__ stok, int* __restrict__ sidv)
{
    __shared__ int part_l[NHB][NSEG];
    __shared__ int segoff[NSEG + 1];
    __shared__ int basebs[NSEG];
    __shared__ int cnt[NSEG];
    const int tid = threadIdx.x;
    const int b   = blockIdx.x;

    if (tid < NHB * NSEG) part_l[tid >> 5][tid & 31] = partial[tid];
    __syncthreads();

    if (tid < NSEG) {
        int tot_before = 0, tot_s = 0, base = 0;
        for (int bb = 0; bb < NHB; ++bb) {
            const int v = part_l[bb][tid];
            tot_s += v;
            if (bb < b) base += v;
        }
        for (int s = 0; s < NSEG; ++s)
            if (s < tid)
                for (int bb = 0; bb < NHB; ++bb) tot_before += part_l[bb][s];
        segoff[tid] = tot_before;
        basebs[tid] = base;
        cnt[tid]    = 0;
        if (tid == NSEG - 1) segoff[NSEG] = tot_before + tot_s;
    }
    __syncthreads();

    const int t  = b * 1024 + tid;
    const int id = ids[t];
    const int sg = id / SEGSZ;
    const int r  = atomicAdd(&cnt[sg], 1);
    const int pos = segoff[sg] + basebs[sg] + r;
    stok[pos] = t;
    sidv[pos] = id;

    if (b == 0 && tid <= NSEG) seg_off[tid] = segoff[tid];
}

// ---------------- Kernel A v3: streaming gather via global_load_lds ----------------
// block = (row r, segment s). 13 async 1KB chunks (chunk 12 overshoots 512B into
// the next row's data -- unused, in-allocation). One barrier, then lookup.
__global__ __launch_bounds__(256)
void gather_rows(const float* __restrict__ cluster_w,
                 const float* __restrict__ cluster_b,
                 const int*   __restrict__ sidv,
                 const int*   __restrict__ seg_off,
                 __hip_bfloat16* __restrict__ logT)      // [NC][NTOK]
{
    __shared__ float seg[3328];        // 13 x 1024B
    const int bid  = blockIdx.x;
    const int r    = bid >> 5;
    const int s    = bid & 31;
    const int tid  = threadIdx.x;
    const int wave = tid >> 6;
    const int lane = tid & 63;
    const int sbase = s * SEGSZ;

    const float* rowseg = cluster_w + (size_t)r * VOCAB + sbase;

    if (r == NC - 1 && s == NSEG - 1) {
        // last block: no overshoot allowed (table end); plain loads
        const int nf4 = (VOCAB - sbase) >> 2;
        for (int i = tid; i < nf4; i += 256)
            *reinterpret_cast<float4*>(&seg[4 * i]) =
                reinterpret_cast<const float4*>(rowseg)[i];
    } else {
        // wave w -> chunks w, w+4, w+8 (+12 for wave 0); lane contributes 16B
        gload_lds16(rowseg + (wave)      * 256 + lane * 4, &seg[(wave)      * 256]);
        gload_lds16(rowseg + (wave + 4)  * 256 + lane * 4, &seg[(wave + 4)  * 256]);
        gload_lds16(rowseg + (wave + 8)  * 256 + lane * 4, &seg[(wave + 8)  * 256]);
        if (wave == 0)
            gload_lds16(rowseg + 12 * 256 + lane * 4, &seg[12 * 256]);
    }

    const float bias = cluster_b[r];
    const int lo = seg_off[s];
    const int hi = seg_off[s + 1];
    __syncthreads();   // compiler drains vmcnt(0) here -> LDS valid

    for (int i = lo + tid; i < hi; i += 256)
        logT[(size_t)r * NTOK + i] = __float2bfloat16(seg[sidv[i] - sbase] + bias);
}

// ---------------- Kernel B: softmax + fine + MFMA mixture (unchanged) ----------------
__global__ __launch_bounds__(512)
void mix_mfma(const ushort* __restrict__ logT,     // [NC][NTOK] bf16 bits
              const float*  __restrict__ fine_w,
              const ushort* __restrict__ cT,       // [HALF][NC] bf16 bits, L2-hot
              const int*    __restrict__ stok,
              const int*    __restrict__ sidv,
              float*        __restrict__ out)
{
    __shared__ uint4 ldsA[32][33];
    __shared__ float redu[32][17];
    __shared__ int stok_l[32], sid_l[32];

    const int tid  = threadIdx.x;
    const int base = blockIdx.x * 32;

    if (tid < 32) { stok_l[tid] = stok[base + tid]; sid_l[tid] = sidv[base + tid]; }

    const int s = tid & 31;
    const int g = tid >> 5;
    float v[16];
#pragma unroll
    for (int i = 0; i < 16; ++i) {
        const unsigned u = logT[(size_t)(g * 16 + i) * NTOK + base + s];
        v[i] = __uint_as_float(u << 16);
    }
    float m = v[0];
#pragma unroll
    for (int i = 1; i < 16; ++i) m = fmaxf(m, v[i]);
    redu[s][g] = m;
    __syncthreads();
    float M = redu[s][0];
#pragma unroll
    for (int i = 1; i < 16; ++i) M = fmaxf(M, redu[s][i]);
    __syncthreads();
    float sum = 0.f;
#pragma unroll
    for (int i = 0; i < 16; ++i) { v[i] = __expf(v[i] - M); sum += v[i]; }
    redu[s][g] = sum;
    __syncthreads();
    float tot = 0.f;
#pragma unroll
    for (int i = 0; i < 16; ++i) tot += redu[s][i];
    const float inv = 1.f / tot;

    {
        uint4 u0, u1;
        u0.x = bfpk(v[0] * inv,  v[1] * inv);
        u0.y = bfpk(v[2] * inv,  v[3] * inv);
        u0.z = bfpk(v[4] * inv,  v[5] * inv);
        u0.w = bfpk(v[6] * inv,  v[7] * inv);
        u1.x = bfpk(v[8] * inv,  v[9] * inv);
        u1.y = bfpk(v[10] * inv, v[11] * inv);
        u1.z = bfpk(v[12] * inv, v[13] * inv);
        u1.w = bfpk(v[14] * inv, v[15] * inv);
        ldsA[s][2 * g]     = u0;
        ldsA[s][2 * g + 1] = u1;
    }

    {
        const int sl = tid >> 4, l16 = tid & 15;
        const float4* fs = reinterpret_cast<const float4*>(fine_w + (size_t)sid_l[sl] * HALF);
        float4* fd = reinterpret_cast<float4*>(out + (size_t)stok_l[sl] * 512);
#pragma unroll
        for (int p = 0; p < 4; ++p) fd[l16 + 16 * p] = fs[l16 + 16 * p];
    }
    __syncthreads();

    const int w    = tid >> 6;
    const int lane = tid & 63;
    const int arow = (w & 1) * 16 + (lane & 15);
    const int ngrp = (w >> 1) * 4;
    f32x4 acc[4];
#pragma unroll
    for (int q = 0; q < 4; ++q) acc[q] = (f32x4){0.f, 0.f, 0.f, 0.f};

    for (int ch = 0; ch < 8; ++ch) {
        const frag a = *reinterpret_cast<const frag*>(&ldsA[arow][ch * 4 + (lane >> 4)]);
#pragma unroll
        for (int q = 0; q < 4; ++q) {
            const int n = (ngrp + q) * 16 + (lane & 15);
            const frag b = *reinterpret_cast<const frag*>(
                cT + (size_t)n * NC + ch * 32 + (lane >> 4) * 8);
            acc[q] = __builtin_amdgcn_mfma_f32_16x16x32_bf16(a, b, acc[q], 0, 0, 0);
        }
    }

#pragma unroll
    for (int q = 0; q < 4; ++q) {
        const int col = (ngrp + q) * 16 + (lane & 15);
#pragma unroll
        for (int r = 0; r < 4; ++r) {
            const int srow = (w & 1) * 16 + (lane >> 4) * 4 + r;
            out[(size_t)stok_l[srow] * 512 + 256 + col] = acc[q][r];
        }
    }
}

extern "C" void kernel_launch(void* const* d_in, const int* in_sizes, int n_in,
                              void* d_out, int out_size, void* d_ws, size_t ws_size,
                              hipStream_t stream) {
    const int*   ids       = (const int*)  d_in[0];
    const float* fine_w    = (const float*)d_in[1];
    const float* coarse_w  = (const float*)d_in[2];
    const float* cluster_w = (const float*)d_in[3];
    const float* cluster_b = (const float*)d_in[4];
    float*       out       = (float*)d_out;

    int* partial = (int*)d_ws;                    // [NHB*NSEG]
    int* seg_off = partial + NHB * NSEG;          // [NSEG+1] (pad 64)
    int* stok    = seg_off + 64;                  // [NTOK]
    int* sidv    = stok + NTOK;                   // [NTOK]
    __hip_bfloat16* logT = (__hip_bfloat16*)(sidv + NTOK);   // [NC*NTOK]
    ushort* cT = (ushort*)(logT + (size_t)NC * NTOK);        // [HALF*NC]

    const size_t need = (size_t)(NHB * NSEG + 64 + 2 * NTOK) * sizeof(int)
                      + (size_t)NC * NTOK * 2 + (size_t)HALF * NC * 2;
    if (ws_size < need) return;   // not expected

    hipLaunchKernelGGL(prep1, dim3(2 * NHB), dim3(1024), 0, stream,
                       ids, coarse_w, partial, cT);
    hipLaunchKernelGGL(prep2, dim3(NHB), dim3(1024), 0, stream,
                       ids, partial, seg_off, stok, sidv);
    hipLaunchKernelGGL(gather_rows, dim3(NC * NSEG), dim3(256), 0, stream,
                       cluster_w, cluster_b, sidv, seg_off, logT);
    hipLaunchKernelGGL(mix_mfma, dim3(NTOK / 32), dim3(512), 0, stream,
                       (const ushort*)logT, fine_w, cT, stok, sidv, out);
}